// Round 1
// baseline (982.515 us; speedup 1.0000x reference)
//
#include <hip/hip_runtime.h>
#include <math.h>
#include <stdint.h>

#define BATCH 16
#define RDIM 2048
#define UDIM 2048
#define DDIM 1024

typedef __attribute__((ext_vector_type(8))) short short8;
typedef __attribute__((ext_vector_type(4))) float f32x4;
typedef __attribute__((ext_vector_type(8))) unsigned short ushort8;
typedef __attribute__((ext_vector_type(4))) unsigned short ushort4v;
typedef __attribute__((ext_vector_type(4))) float float4v;

__device__ __forceinline__ float bf2f(unsigned short u) {
  unsigned int x = ((unsigned int)u) << 16;
  return __builtin_bit_cast(float, x);
}
__device__ __forceinline__ unsigned short f2bf(float f) {
  unsigned int x = __builtin_bit_cast(unsigned int, f);
  unsigned int r = (x + 0x7fffu + ((x >> 16) & 1u)) >> 16;
  return (unsigned short)r;
}

// global -> LDS direct copy, 16B per lane. LDS dest must be wave-uniform base;
// HW writes base + lane*16.
__device__ __forceinline__ void gload_lds16(const void* g, void* l) {
  __builtin_amdgcn_global_load_lds(
      (const __attribute__((address_space(1))) void*)(uintptr_t)g,
      (__attribute__((address_space(3))) void*)(uint32_t)(uintptr_t)l,
      16, 0, 0);
}

// ---------------- conversions ----------------

__global__ __launch_bounds__(256) void k_conv_bf16(const float* __restrict__ in,
                                                   unsigned short* __restrict__ out,
                                                   float scale) {
  const long i = ((long)blockIdx.x * 256 + threadIdx.x) * 8;
  float4v a = *(const float4v*)(in + i);
  float4v b = *(const float4v*)(in + i + 4);
  ushort8 o;
#pragma unroll
  for (int j = 0; j < 4; ++j) o[j] = f2bf(a[j] * scale);
#pragma unroll
  for (int j = 0; j < 4; ++j) o[4 + j] = f2bf(b[j] * scale);
  *(ushort8*)(out + i) = o;
}

// out[c*rows + r] = bf16(in[r*cols + c])
__global__ void k_transpose_bf16(const float* __restrict__ in,
                                 unsigned short* __restrict__ out,
                                 int rows, int cols, long sIn, long sOut) {
  __shared__ unsigned short tile[64][65];
  const long bz = blockIdx.z;
  in += bz * sIn;
  out += bz * sOut;
  const int r0 = blockIdx.x * 64;
  const int c0 = blockIdx.y * 64;
  const int tx = threadIdx.x;  // 64
  const int ty = threadIdx.y;  // 4
#pragma unroll
  for (int i = 0; i < 16; ++i) {
    const int r = ty + i * 4;
    tile[r][tx] = f2bf(in[(long)(r0 + r) * cols + c0 + tx]);
  }
  __syncthreads();
#pragma unroll
  for (int i = 0; i < 16; ++i) {
    const int r = ty + i * 4;
    out[(long)(c0 + r) * rows + r0 + tx] = tile[tx][r];
  }
}

// ---------------- GEMM: C[M,N] = A[M,K] * B[N,K]^T, all bf16 in, fp32 acc ----
// EPI 0: store bf16
// EPI 1: store bf16 relu(acc + bias[col])
// EPI 2: store fp32 acc + bias[col] + bf2f(res[row,col])

template <int EPI>
__global__ __launch_bounds__(256) void gemm_bt(
    const unsigned short* __restrict__ A, const unsigned short* __restrict__ B,
    void* __restrict__ Cout, int N, int K, long sA, long sB, long sC,
    const float* __restrict__ bias, const unsigned short* __restrict__ res) {
  __shared__ unsigned short As[128 * 64];
  __shared__ unsigned short Bs[128 * 64];

  const int bz = blockIdx.z;
  const unsigned short* Ab = A + (long)bz * sA;
  const unsigned short* Bb = B + (long)bz * sB;

  const int tid = threadIdx.x;
  const int wave = tid >> 6;
  const int lane = tid & 63;
  const int wr = wave >> 1;
  const int wc = wave & 1;
  const long rowBase = (long)blockIdx.x * 128;
  const long colBase = (long)blockIdx.y * 128;

  f32x4 acc[4][4] = {};

  const int ci0 = wave * 64 + lane;
  const int laneM = lane & 15;
  const int laneK = (lane >> 4) << 3;

  const int nTiles = K >> 6;
  for (int kt = 0; kt < nTiles; ++kt) {
    const int k0 = kt << 6;
    __syncthreads();
#pragma unroll
    for (int it = 0; it < 4; ++it) {
      const int ci = it * 256 + ci0;     // 16B chunk id, 0..1023
      const int r = ci >> 3;             // tile row 0..127
      const int kk = (ci & 7) << 3;      // k offset within tile
      gload_lds16(Ab + (rowBase + r) * K + k0 + kk,
                  &As[(size_t)(it * 256 + wave * 64) * 8]);
      gload_lds16(Bb + (colBase + r) * K + k0 + kk,
                  &Bs[(size_t)(it * 256 + wave * 64) * 8]);
    }
    __syncthreads();
#pragma unroll
    for (int ks = 0; ks < 2; ++ks) {
      short8 a[4], b[4];
#pragma unroll
      for (int i = 0; i < 4; ++i)
        a[i] = *(const short8*)&As[(wr * 64 + i * 16 + laneM) * 64 + ks * 32 + laneK];
#pragma unroll
      for (int j = 0; j < 4; ++j)
        b[j] = *(const short8*)&Bs[(wc * 64 + j * 16 + laneM) * 64 + ks * 32 + laneK];
#pragma unroll
      for (int i = 0; i < 4; ++i)
#pragma unroll
        for (int j = 0; j < 4; ++j)
          acc[i][j] =
              __builtin_amdgcn_mfma_f32_16x16x32_bf16(a[i], b[j], acc[i][j], 0, 0, 0);
    }
  }

  const long r0 = rowBase + wr * 64;
  const long c0 = colBase + wc * 64;
  const int cr = (lane >> 4) << 2;
  const int cc = lane & 15;

  if constexpr (EPI == 0) {
    unsigned short* C = (unsigned short*)Cout + (long)bz * sC;
#pragma unroll
    for (int i = 0; i < 4; ++i)
#pragma unroll
      for (int j = 0; j < 4; ++j)
#pragma unroll
        for (int jj = 0; jj < 4; ++jj)
          C[(r0 + i * 16 + cr + jj) * N + (c0 + j * 16 + cc)] = f2bf(acc[i][j][jj]);
  } else if constexpr (EPI == 1) {
    unsigned short* C = (unsigned short*)Cout;
#pragma unroll
    for (int i = 0; i < 4; ++i)
#pragma unroll
      for (int j = 0; j < 4; ++j)
#pragma unroll
        for (int jj = 0; jj < 4; ++jj) {
          const long col = c0 + j * 16 + cc;
          float v = acc[i][j][jj] + bias[col];
          v = fmaxf(v, 0.f);
          C[(r0 + i * 16 + cr + jj) * N + col] = f2bf(v);
        }
  } else {
    float* C = (float*)Cout;
#pragma unroll
    for (int i = 0; i < 4; ++i)
#pragma unroll
      for (int j = 0; j < 4; ++j)
#pragma unroll
        for (int jj = 0; jj < 4; ++jj) {
          const long row = r0 + i * 16 + cr + jj;
          const long col = c0 + j * 16 + cc;
          C[row * N + col] = acc[i][j][jj] + bias[col] + bf2f(res[row * N + col]);
        }
  }
}

// ---------------- softmax over rows of S (in-place, bf16) ----------------

__global__ __launch_bounds__(256) void k_softmax(unsigned short* __restrict__ S) {
  __shared__ float red[8];
  const long base = (long)blockIdx.x * UDIM;
  const int t = threadIdx.x;
  ushort8 raw = *(const ushort8*)(S + base + t * 8);
  float v[8];
  float mx = -3.0e38f;
#pragma unroll
  for (int j = 0; j < 8; ++j) {
    v[j] = bf2f(raw[j]);
    mx = fmaxf(mx, v[j]);
  }
#pragma unroll
  for (int m = 32; m >= 1; m >>= 1) mx = fmaxf(mx, __shfl_xor(mx, m));
  const int wv = t >> 6;
  if ((t & 63) == 0) red[wv] = mx;
  __syncthreads();
  mx = fmaxf(fmaxf(red[0], red[1]), fmaxf(red[2], red[3]));
  float s = 0.f;
#pragma unroll
  for (int j = 0; j < 8; ++j) {
    v[j] = __expf(v[j] - mx);
    s += v[j];
  }
#pragma unroll
  for (int m = 32; m >= 1; m >>= 1) s += __shfl_xor(s, m);
  if ((t & 63) == 0) red[4 + wv] = s;
  __syncthreads();
  s = red[4] + red[5] + red[6] + red[7];
  const float rs = 1.f / s;
  ushort8 o;
#pragma unroll
  for (int j = 0; j < 8; ++j) o[j] = f2bf(v[j] * rs);
  *(ushort8*)(S + base + t * 8) = o;
}

// ---------------- X = LN(Q + V_att) -> bf16 ----------------

__global__ __launch_bounds__(256) void k_addln_bf16(
    const float* __restrict__ Q, const unsigned short* __restrict__ Va,
    unsigned short* __restrict__ X, const float* __restrict__ gamma,
    const float* __restrict__ beta) {
  __shared__ float red[8];
  const long base = (long)blockIdx.x * DDIM;
  const int t = threadIdx.x;
  float4v q = *(const float4v*)(Q + base + t * 4);
  ushort4v a = *(const ushort4v*)(Va + base + t * 4);
  float x[4];
  float s = 0.f, ss = 0.f;
#pragma unroll
  for (int j = 0; j < 4; ++j) {
    x[j] = q[j] + bf2f(a[j]);
    s += x[j];
    ss += x[j] * x[j];
  }
#pragma unroll
  for (int m = 32; m >= 1; m >>= 1) {
    s += __shfl_xor(s, m);
    ss += __shfl_xor(ss, m);
  }
  const int wv = t >> 6;
  if ((t & 63) == 0) {
    red[wv] = s;
    red[4 + wv] = ss;
  }
  __syncthreads();
  s = red[0] + red[1] + red[2] + red[3];
  ss = red[4] + red[5] + red[6] + red[7];
  const float mu = s * (1.f / DDIM);
  const float var = ss * (1.f / DDIM) - mu * mu;
  const float rstd = rsqrtf(var + 1e-6f);
  ushort4v o;
#pragma unroll
  for (int j = 0; j < 4; ++j) {
    const int c = t * 4 + j;
    o[j] = f2bf(gamma[c] * ((x[j] - mu) * rstd) + beta[c]);
  }
  *(ushort4v*)(X + base + t * 4) = o;
}

// ---------------- in-place LN on fp32 rows ----------------

__global__ __launch_bounds__(256) void k_ln_inplace(float* __restrict__ Y,
                                                    const float* __restrict__ gamma,
                                                    const float* __restrict__ beta) {
  __shared__ float red[8];
  const long base = (long)blockIdx.x * DDIM;
  const int t = threadIdx.x;
  float4v y = *(const float4v*)(Y + base + t * 4);
  float s = 0.f, ss = 0.f;
#pragma unroll
  for (int j = 0; j < 4; ++j) {
    s += y[j];
    ss += y[j] * y[j];
  }
#pragma unroll
  for (int m = 32; m >= 1; m >>= 1) {
    s += __shfl_xor(s, m);
    ss += __shfl_xor(ss, m);
  }
  const int wv = t >> 6;
  if ((t & 63) == 0) {
    red[wv] = s;
    red[4 + wv] = ss;
  }
  __syncthreads();
  s = red[0] + red[1] + red[2] + red[3];
  ss = red[4] + red[5] + red[6] + red[7];
  const float mu = s * (1.f / DDIM);
  const float var = ss * (1.f / DDIM) - mu * mu;
  const float rstd = rsqrtf(var + 1e-6f);
  float4v o;
#pragma unroll
  for (int j = 0; j < 4; ++j) {
    const int c = t * 4 + j;
    o[j] = gamma[c] * ((y[j] - mu) * rstd) + beta[c];
  }
  *(float4v*)(Y + base + t * 4) = o;
}

// ---------------- launch ----------------

extern "C" void kernel_launch(void* const* d_in, const int* in_sizes, int n_in,
                              void* d_out, int out_size, void* d_ws, size_t ws_size,
                              hipStream_t stream) {
  const float* Q = (const float*)d_in[0];
  const float* Kin = (const float*)d_in[1];
  const float* V = (const float*)d_in[2];
  const float* W1 = (const float*)d_in[3];
  const float* b1 = (const float*)d_in[4];
  const float* W2 = (const float*)d_in[5];
  const float* b2 = (const float*)d_in[6];
  const float* gamma = (const float*)d_in[7];
  const float* beta = (const float*)d_in[8];
  float* out = (float*)d_out;

  const long nQ = (long)BATCH * RDIM * DDIM;  // 33.5M
  const long nK = (long)BATCH * UDIM * DDIM;  // 33.5M
  const long nS = (long)BATCH * RDIM * UDIM;  // 67.1M

  // workspace layout (~388 MB total)
  char* w = (char*)d_ws;
  unsigned short* Qb = (unsigned short*)w;  w += nQ * 2;
  unsigned short* Kb = (unsigned short*)w;  w += nK * 2;
  unsigned short* Vt = (unsigned short*)w;  w += nK * 2;
  unsigned short* S  = (unsigned short*)w;  w += nS * 2;
  unsigned short* X  = (unsigned short*)w;  w += nQ * 2;
  unsigned short* W1t = (unsigned short*)w; w += (long)DDIM * DDIM * 2;
  unsigned short* W2t = (unsigned short*)w; w += (long)DDIM * DDIM * 2;
  unsigned short* Va = Qb;  // reuse: Qb dead after S-gemm
  unsigned short* H  = S;   // reuse: S dead after PV-gemm

  const float scale = 1.0f / sqrtf(1024.0f + 1e-8f);  // matches sqrt(D+eps) in fp32

  k_conv_bf16<<<nQ / 2048, 256, 0, stream>>>(Q, Qb, scale);
  k_conv_bf16<<<nK / 2048, 256, 0, stream>>>(Kin, Kb, 1.0f);
  k_transpose_bf16<<<dim3(UDIM / 64, DDIM / 64, BATCH), dim3(64, 4), 0, stream>>>(
      V, Vt, UDIM, DDIM, (long)UDIM * DDIM, (long)UDIM * DDIM);
  k_transpose_bf16<<<dim3(DDIM / 64, DDIM / 64, 1), dim3(64, 4), 0, stream>>>(
      W1, W1t, DDIM, DDIM, 0, 0);
  k_transpose_bf16<<<dim3(DDIM / 64, DDIM / 64, 1), dim3(64, 4), 0, stream>>>(
      W2, W2t, DDIM, DDIM, 0, 0);

  // S = (Q/scale) @ K^T   [per batch 2048x2048, K=1024]
  gemm_bt<0><<<dim3(RDIM / 128, UDIM / 128, BATCH), 256, 0, stream>>>(
      Qb, Kb, S, UDIM, DDIM, (long)RDIM * DDIM, (long)UDIM * DDIM, (long)RDIM * UDIM,
      nullptr, nullptr);
  k_softmax<<<BATCH * RDIM, 256, 0, stream>>>(S);
  // V_att = P @ V   [per batch 2048x1024, K=2048]
  gemm_bt<0><<<dim3(RDIM / 128, DDIM / 128, BATCH), 256, 0, stream>>>(
      S, Vt, Va, DDIM, UDIM, (long)RDIM * UDIM, (long)DDIM * UDIM, (long)RDIM * DDIM,
      nullptr, nullptr);
  // X = LN(Q + V_att)
  k_addln_bf16<<<BATCH * RDIM, 256, 0, stream>>>(Q, Va, X, gamma, beta);
  // H = relu(X @ W1 + b1)   [32768x1024, K=1024]
  gemm_bt<1><<<dim3(BATCH * RDIM / 128, DDIM / 128, 1), 256, 0, stream>>>(
      X, W1t, H, DDIM, DDIM, 0, 0, 0, b1, nullptr);
  // out = H @ W2 + b2 + X  (pre-LN, fp32)
  gemm_bt<2><<<dim3(BATCH * RDIM / 128, DDIM / 128, 1), 256, 0, stream>>>(
      H, W2t, out, DDIM, DDIM, 0, 0, 0, b2, X);
  // out = LN(out)  in-place
  k_ln_inplace<<<BATCH * RDIM, 256, 0, stream>>>(out, gamma, beta);
}

// Round 2
// 701.744 us; speedup vs baseline: 1.4001x; 1.4001x over previous
//
#include <hip/hip_runtime.h>
#include <math.h>
#include <stdint.h>

#define BATCH 16
#define RDIM 2048
#define UDIM 2048
#define DDIM 1024

typedef __attribute__((ext_vector_type(8))) short short8;
typedef __attribute__((ext_vector_type(4))) float f32x4;
typedef __attribute__((ext_vector_type(8))) unsigned short ushort8;
typedef __attribute__((ext_vector_type(4))) unsigned short ushort4v;
typedef __attribute__((ext_vector_type(4))) float float4v;

__device__ __forceinline__ float bf2f(unsigned short u) {
  unsigned int x = ((unsigned int)u) << 16;
  return __builtin_bit_cast(float, x);
}
__device__ __forceinline__ unsigned short f2bf(float f) {
  unsigned int x = __builtin_bit_cast(unsigned int, f);
  unsigned int r = (x + 0x7fffu + ((x >> 16) & 1u)) >> 16;
  return (unsigned short)r;
}

// global -> LDS direct copy, 16B per lane. LDS dest is wave-uniform base;
// HW writes base + lane*16. Global src address is per-lane (pre-swizzle there).
__device__ __forceinline__ void gload_lds16(const void* g, void* l) {
  __builtin_amdgcn_global_load_lds(
      (const __attribute__((address_space(1))) void*)(uintptr_t)g,
      (__attribute__((address_space(3))) void*)(uint32_t)(uintptr_t)l,
      16, 0, 0);
}

// ---------------- conversions ----------------

__global__ __launch_bounds__(256) void k_conv_bf16(const float* __restrict__ in,
                                                   unsigned short* __restrict__ out,
                                                   float scale) {
  const long i = ((long)blockIdx.x * 256 + threadIdx.x) * 8;
  float4v a = *(const float4v*)(in + i);
  float4v b = *(const float4v*)(in + i + 4);
  ushort8 o;
#pragma unroll
  for (int j = 0; j < 4; ++j) o[j] = f2bf(a[j] * scale);
#pragma unroll
  for (int j = 0; j < 4; ++j) o[4 + j] = f2bf(b[j] * scale);
  *(ushort8*)(out + i) = o;
}

// out[c*rows + r] = bf16(in[r*cols + c])
__global__ void k_transpose_bf16(const float* __restrict__ in,
                                 unsigned short* __restrict__ out,
                                 int rows, int cols, long sIn, long sOut) {
  __shared__ unsigned short tile[64][65];
  const long bz = blockIdx.z;
  in += bz * sIn;
  out += bz * sOut;
  const int r0 = blockIdx.x * 64;
  const int c0 = blockIdx.y * 64;
  const int tx = threadIdx.x;  // 64
  const int ty = threadIdx.y;  // 4
#pragma unroll
  for (int i = 0; i < 16; ++i) {
    const int r = ty + i * 4;
    tile[r][tx] = f2bf(in[(long)(r0 + r) * cols + c0 + tx]);
  }
  __syncthreads();
#pragma unroll
  for (int i = 0; i < 16; ++i) {
    const int r = ty + i * 4;
    out[(long)(c0 + r) * rows + r0 + tx] = tile[tx][r];
  }
}

// ---------------- GEMM: C[M,N] = A[M,K] * B[N,K]^T, bf16 in, fp32 acc -------
// 256x256 tile, BK=64, 512 threads = 8 waves (2Mx4N), per-wave 128x64 output.
// LDS 128 KiB: double-buffered A/B K-tiles, XOR-swizzled (read side), inverse
// swizzle pre-applied on the global_load_lds source address (LDS dest linear).
// Pipeline: counted vmcnt(8) (never 0 in main loop), raw s_barrier, setprio
// around second MFMA half.
// EPI 0: store bf16
// EPI 1: store bf16 relu(acc + bias[col])
// EPI 2: store fp32 acc + bias[col] + bf2f(res[row,col])

template <int EPI>
__global__ __launch_bounds__(512, 2) void gemm_bt(
    const unsigned short* __restrict__ A, const unsigned short* __restrict__ B,
    void* __restrict__ Cout, int N, int K, long sA, long sB, long sC,
    const float* __restrict__ bias, const unsigned short* __restrict__ res) {
  __shared__ __align__(32) unsigned short As[2][256 * 64];
  __shared__ __align__(32) unsigned short Bs[2][256 * 64];

  const int bz = blockIdx.z;
  const unsigned short* Ab = A + (long)bz * sA;
  const unsigned short* Bb = B + (long)bz * sB;

  const int tid = threadIdx.x;
  const int w = tid >> 6;    // wave 0..7
  const int lane = tid & 63;
  const int wm = w >> 2;     // 0..1
  const int wn = w & 3;      // 0..3
  const long rowBase = (long)blockIdx.x * 256;
  const long colBase = (long)blockIdx.y * 256;

  // ---- staging addresses (inverse-swizzled global source, linear LDS dest) --
  // Linear LDS byte p = (w*4+q)*1024 + lane*16 within a 32 KiB operand slot.
  // r = w*32 + q*8 + (lane>>3); stored logical col bytes = (p&127) ^ ((r&7)<<4)
  //   = (((lane&7) ^ (lane>>3)) << 4).
  const int stR = w * 32 + (lane >> 3);
  const int stC = ((lane & 7) ^ (lane >> 3)) << 3;  // elements (16B = 8 elems)
  const unsigned short* gA0 = Ab + (rowBase + stR) * (long)K + stC;
  const unsigned short* gB0 = Bb + (colBase + stR) * (long)K + stC;
  char* lA0 = (char*)&As[0][0] + w * 4096;
  char* lB0 = (char*)&Bs[0][0] + w * 4096;

  auto STAGE = [&](int slot, int kt) {
    const unsigned short* ga = gA0 + (long)kt * 64;
    const unsigned short* gb = gB0 + (long)kt * 64;
    char* la = lA0 + slot * 32768;
    char* lb = lB0 + slot * 32768;
#pragma unroll
    for (int q = 0; q < 4; ++q) {
      gload_lds16(ga + (long)q * 8 * K, la + q * 1024);
      gload_lds16(gb + (long)q * 8 * K, lb + q * 1024);
    }
  };

  // ---- fragment read addressing (swizzled) ----
  const int laneM = lane & 15;
  const int laneQ = lane >> 4;  // 0..3
  // phys byte = row*128 + ((ks*64 | laneQ*16) ^ ((laneM&7)<<4))
  const int co0 = (laneQ << 4) ^ ((laneM & 7) << 4);

  f32x4 acc[8][4] = {};

  const int NT = K >> 6;
  STAGE(0, 0);
  STAGE(1, 1);
  asm volatile("s_waitcnt vmcnt(8)" ::: "memory");  // tile 0 landed
  __builtin_amdgcn_s_barrier();

  for (int t = 0; t < NT; ++t) {
    const int cur = t & 1;
    const char* Ap = (const char*)&As[cur][0] + (wm * 128 + laneM) * 128;
    const char* Bp = (const char*)&Bs[cur][0] + (wn * 64 + laneM) * 128;

    short8 a[8][2], b[4][2];
#pragma unroll
    for (int ks = 0; ks < 2; ++ks) {
      const int co = co0 ^ (ks << 6);
#pragma unroll
      for (int m = 0; m < 4; ++m) a[m][ks] = *(const short8*)(Ap + m * 2048 + co);
#pragma unroll
      for (int n = 0; n < 4; ++n) b[n][ks] = *(const short8*)(Bp + n * 2048 + co);
#pragma unroll
      for (int m = 4; m < 8; ++m) a[m][ks] = *(const short8*)(Ap + m * 2048 + co);
    }
    // first half MFMA (compiler interleaves with the ds_reads above)
#pragma unroll
    for (int m = 0; m < 4; ++m)
#pragma unroll
      for (int n = 0; n < 4; ++n)
#pragma unroll
        for (int ks = 0; ks < 2; ++ks)
          acc[m][n] = __builtin_amdgcn_mfma_f32_16x16x32_bf16(a[m][ks], b[n][ks],
                                                              acc[m][n], 0, 0, 0);
    // all my ds_reads of slot `cur` complete, then all waves' -> slot free
    asm volatile("s_waitcnt lgkmcnt(0)" ::: "memory");
    __builtin_amdgcn_s_barrier();
    if (t + 2 < NT) STAGE(cur, t + 2);
    __builtin_amdgcn_s_setprio(1);
#pragma unroll
    for (int m = 4; m < 8; ++m)
#pragma unroll
      for (int n = 0; n < 4; ++n)
#pragma unroll
        for (int ks = 0; ks < 2; ++ks)
          acc[m][n] = __builtin_amdgcn_mfma_f32_16x16x32_bf16(a[m][ks], b[n][ks],
                                                              acc[m][n], 0, 0, 0);
    __builtin_amdgcn_s_setprio(0);
    // tile t+1 must be landed before next iteration reads it; t+2's 8 loads
    // may stay in flight (counted vmcnt, FIFO per wave).
    if (t + 2 < NT) {
      asm volatile("s_waitcnt vmcnt(8)" ::: "memory");
    } else {
      asm volatile("s_waitcnt vmcnt(0)" ::: "memory");
    }
    __builtin_amdgcn_s_barrier();
  }

  const long r0 = rowBase + wm * 128;
  const long c0 = colBase + wn * 64;
  const int cr = (lane >> 4) << 2;
  const int cc = lane & 15;

  if constexpr (EPI == 0) {
    unsigned short* C = (unsigned short*)Cout + (long)bz * sC;
#pragma unroll
    for (int i = 0; i < 8; ++i)
#pragma unroll
      for (int j = 0; j < 4; ++j)
#pragma unroll
        for (int jj = 0; jj < 4; ++jj)
          C[(r0 + i * 16 + cr + jj) * N + (c0 + j * 16 + cc)] = f2bf(acc[i][j][jj]);
  } else if constexpr (EPI == 1) {
    unsigned short* C = (unsigned short*)Cout;
#pragma unroll
    for (int i = 0; i < 8; ++i)
#pragma unroll
      for (int j = 0; j < 4; ++j)
#pragma unroll
        for (int jj = 0; jj < 4; ++jj) {
          const long col = c0 + j * 16 + cc;
          float v = acc[i][j][jj] + bias[col];
          v = fmaxf(v, 0.f);
          C[(r0 + i * 16 + cr + jj) * N + col] = f2bf(v);
        }
  } else {
    float* C = (float*)Cout;
#pragma unroll
    for (int i = 0; i < 8; ++i)
#pragma unroll
      for (int j = 0; j < 4; ++j)
#pragma unroll
        for (int jj = 0; jj < 4; ++jj) {
          const long row = r0 + i * 16 + cr + jj;
          const long col = c0 + j * 16 + cc;
          C[row * N + col] = acc[i][j][jj] + bias[col] + bf2f(res[row * N + col]);
        }
  }
}

// ---------------- softmax over rows of S (in-place, bf16) ----------------

__global__ __launch_bounds__(256) void k_softmax(unsigned short* __restrict__ S) {
  __shared__ float red[8];
  const long base = (long)blockIdx.x * UDIM;
  const int t = threadIdx.x;
  ushort8 raw = *(const ushort8*)(S + base + t * 8);
  float v[8];
  float mx = -3.0e38f;
#pragma unroll
  for (int j = 0; j < 8; ++j) {
    v[j] = bf2f(raw[j]);
    mx = fmaxf(mx, v[j]);
  }
#pragma unroll
  for (int m = 32; m >= 1; m >>= 1) mx = fmaxf(mx, __shfl_xor(mx, m));
  const int wv = t >> 6;
  if ((t & 63) == 0) red[wv] = mx;
  __syncthreads();
  mx = fmaxf(fmaxf(red[0], red[1]), fmaxf(red[2], red[3]));
  float s = 0.f;
#pragma unroll
  for (int j = 0; j < 8; ++j) {
    v[j] = __expf(v[j] - mx);
    s += v[j];
  }
#pragma unroll
  for (int m = 32; m >= 1; m >>= 1) s += __shfl_xor(s, m);
  if ((t & 63) == 0) red[4 + wv] = s;
  __syncthreads();
  s = red[4] + red[5] + red[6] + red[7];
  const float rs = 1.f / s;
  ushort8 o;
#pragma unroll
  for (int j = 0; j < 8; ++j) o[j] = f2bf(v[j] * rs);
  *(ushort8*)(S + base + t * 8) = o;
}

// ---------------- X = LN(Q + V_att) -> bf16 ----------------

__global__ __launch_bounds__(256) void k_addln_bf16(
    const float* __restrict__ Q, const unsigned short* __restrict__ Va,
    unsigned short* __restrict__ X, const float* __restrict__ gamma,
    const float* __restrict__ beta) {
  __shared__ float red[8];
  const long base = (long)blockIdx.x * DDIM;
  const int t = threadIdx.x;
  float4v q = *(const float4v*)(Q + base + t * 4);
  ushort4v a = *(const ushort4v*)(Va + base + t * 4);
  float x[4];
  float s = 0.f, ss = 0.f;
#pragma unroll
  for (int j = 0; j < 4; ++j) {
    x[j] = q[j] + bf2f(a[j]);
    s += x[j];
    ss += x[j] * x[j];
  }
#pragma unroll
  for (int m = 32; m >= 1; m >>= 1) {
    s += __shfl_xor(s, m);
    ss += __shfl_xor(ss, m);
  }
  const int wv = t >> 6;
  if ((t & 63) == 0) {
    red[wv] = s;
    red[4 + wv] = ss;
  }
  __syncthreads();
  s = red[0] + red[1] + red[2] + red[3];
  ss = red[4] + red[5] + red[6] + red[7];
  const float mu = s * (1.f / DDIM);
  const float var = ss * (1.f / DDIM) - mu * mu;
  const float rstd = rsqrtf(var + 1e-6f);
  ushort4v o;
#pragma unroll
  for (int j = 0; j < 4; ++j) {
    const int c = t * 4 + j;
    o[j] = f2bf(gamma[c] * ((x[j] - mu) * rstd) + beta[c]);
  }
  *(ushort4v*)(X + base + t * 4) = o;
}

// ---------------- in-place LN on fp32 rows ----------------

__global__ __launch_bounds__(256) void k_ln_inplace(float* __restrict__ Y,
                                                    const float* __restrict__ gamma,
                                                    const float* __restrict__ beta) {
  __shared__ float red[8];
  const long base = (long)blockIdx.x * DDIM;
  const int t = threadIdx.x;
  float4v y = *(const float4v*)(Y + base + t * 4);
  float s = 0.f, ss = 0.f;
#pragma unroll
  for (int j = 0; j < 4; ++j) {
    s += y[j];
    ss += y[j] * y[j];
  }
#pragma unroll
  for (int m = 32; m >= 1; m >>= 1) {
    s += __shfl_xor(s, m);
    ss += __shfl_xor(ss, m);
  }
  const int wv = t >> 6;
  if ((t & 63) == 0) {
    red[wv] = s;
    red[4 + wv] = ss;
  }
  __syncthreads();
  s = red[0] + red[1] + red[2] + red[3];
  ss = red[4] + red[5] + red[6] + red[7];
  const float mu = s * (1.f / DDIM);
  const float var = ss * (1.f / DDIM) - mu * mu;
  const float rstd = rsqrtf(var + 1e-6f);
  float4v o;
#pragma unroll
  for (int j = 0; j < 4; ++j) {
    const int c = t * 4 + j;
    o[j] = gamma[c] * ((y[j] - mu) * rstd) + beta[c];
  }
  *(float4v*)(Y + base + t * 4) = o;
}

// ---------------- launch ----------------

extern "C" void kernel_launch(void* const* d_in, const int* in_sizes, int n_in,
                              void* d_out, int out_size, void* d_ws, size_t ws_size,
                              hipStream_t stream) {
  const float* Q = (const float*)d_in[0];
  const float* Kin = (const float*)d_in[1];
  const float* V = (const float*)d_in[2];
  const float* W1 = (const float*)d_in[3];
  const float* b1 = (const float*)d_in[4];
  const float* W2 = (const float*)d_in[5];
  const float* b2 = (const float*)d_in[6];
  const float* gamma = (const float*)d_in[7];
  const float* beta = (const float*)d_in[8];
  float* out = (float*)d_out;

  const long nQ = (long)BATCH * RDIM * DDIM;  // 33.5M
  const long nK = (long)BATCH * UDIM * DDIM;  // 33.5M
  const long nS = (long)BATCH * RDIM * UDIM;  // 67.1M

  // workspace layout (~388 MB total)
  char* w = (char*)d_ws;
  unsigned short* Qb = (unsigned short*)w;  w += nQ * 2;
  unsigned short* Kb = (unsigned short*)w;  w += nK * 2;
  unsigned short* Vt = (unsigned short*)w;  w += nK * 2;
  unsigned short* S  = (unsigned short*)w;  w += nS * 2;
  unsigned short* X  = (unsigned short*)w;  w += nQ * 2;
  unsigned short* W1t = (unsigned short*)w; w += (long)DDIM * DDIM * 2;
  unsigned short* W2t = (unsigned short*)w; w += (long)DDIM * DDIM * 2;
  unsigned short* Va = Qb;  // reuse: Qb dead after S-gemm
  unsigned short* H  = S;   // reuse: S dead after PV-gemm

  const float scale = 1.0f / sqrtf(1024.0f + 1e-8f);

  k_conv_bf16<<<nQ / 2048, 256, 0, stream>>>(Q, Qb, scale);
  k_conv_bf16<<<nK / 2048, 256, 0, stream>>>(Kin, Kb, 1.0f);
  k_transpose_bf16<<<dim3(UDIM / 64, DDIM / 64, BATCH), dim3(64, 4), 0, stream>>>(
      V, Vt, UDIM, DDIM, (long)UDIM * DDIM, (long)UDIM * DDIM);
  k_transpose_bf16<<<dim3(DDIM / 64, DDIM / 64, 1), dim3(64, 4), 0, stream>>>(
      W1, W1t, DDIM, DDIM, 0, 0);
  k_transpose_bf16<<<dim3(DDIM / 64, DDIM / 64, 1), dim3(64, 4), 0, stream>>>(
      W2, W2t, DDIM, DDIM, 0, 0);

  // S = (Q/scale) @ K^T   [per batch 2048x2048, K=1024]
  gemm_bt<0><<<dim3(RDIM / 256, UDIM / 256, BATCH), 512, 0, stream>>>(
      Qb, Kb, S, UDIM, DDIM, (long)RDIM * DDIM, (long)UDIM * DDIM, (long)RDIM * UDIM,
      nullptr, nullptr);
  k_softmax<<<BATCH * RDIM, 256, 0, stream>>>(S);
  // V_att = P @ V   [per batch 2048x1024, K=2048]
  gemm_bt<0><<<dim3(RDIM / 256, DDIM / 256, BATCH), 512, 0, stream>>>(
      S, Vt, Va, DDIM, UDIM, (long)RDIM * UDIM, (long)DDIM * UDIM, (long)RDIM * DDIM,
      nullptr, nullptr);
  // X = LN(Q + V_att)
  k_addln_bf16<<<BATCH * RDIM, 256, 0, stream>>>(Q, Va, X, gamma, beta);
  // H = relu(X @ W1 + b1)   [32768x1024, K=1024]
  gemm_bt<1><<<dim3(BATCH * RDIM / 256, DDIM / 256, 1), 512, 0, stream>>>(
      X, W1t, H, DDIM, DDIM, 0, 0, 0, b1, nullptr);
  // out = H @ W2 + b2 + X  (pre-LN, fp32)
  gemm_bt<2><<<dim3(BATCH * RDIM / 256, DDIM / 256, 1), 512, 0, stream>>>(
      H, W2t, out, DDIM, DDIM, 0, 0, 0, b2, X);
  // out = LN(out)  in-place
  k_ln_inplace<<<BATCH * RDIM, 256, 0, stream>>>(out, gamma, beta);
}